// Round 8
// baseline (33.017 us; speedup 1.0000x reference)
//
#include <hip/hip_runtime.h>

typedef int   __attribute__((ext_vector_type(4))) i32x4;
typedef float __attribute__((ext_vector_type(4))) f32x4;

constexpr int B_ = 8;
constexpr int N_ = 8192;
constexpr int K_ = 100;
constexpr int PER_BATCH = N_ * K_;                 // 819200 elements
constexpr int QUADS_PER_BATCH = PER_BATCH / 4;     // 204800 quads
constexpr int THREADS = 1024;                      // 16 waves
constexpr int BLOCKS_PER_BATCH = 32;
constexpr int GRID = B_ * BLOCKS_PER_BATCH;        // 256 blocks -> 1/CU (128KB LDS)
constexpr int QUADS_PER_BLOCK = QUADS_PER_BATCH / BLOCKS_PER_BATCH; // 6400
constexpr int FULL_ITERS = QUADS_PER_BLOCK / THREADS;               // 6
constexpr int TAIL = QUADS_PER_BLOCK - FULL_ITERS * THREADS;        // 256

constexpr float RMIN2 = 0.01f;   // 0.1^2
constexpr float RMAX2 = 4.0f;    // 2.0^2

__global__ __launch_bounds__(THREADS, 1)
void repulsive_prior_kernel(const float* __restrict__ positions,  // [B,N,3]
                            const float* __restrict__ cell,       // [B,3,3]
                            const float* __restrict__ offsets,    // [B,N,K,3]
                            const int*   __restrict__ neighbors,  // [B,N,K]
                            const int*   __restrict__ mask,       // [B,N,K]
                            float* __restrict__ out)              // [B]
{
    __shared__ f32x4 spos[N_];            // 128 KB: xyz + pad -> 1 ds_read_b128/gather
    __shared__ float wsum[THREADS / 64];

    const int bid   = blockIdx.x;
    const int b     = bid >> 5;            // 32 blocks per batch
    const int chunk = bid & 31;
    const int t     = (int)threadIdx.x;

    const float* __restrict__ pos_b = positions + (size_t)b * N_ * 3;
    const float* __restrict__ off_b = offsets   + (size_t)b * PER_BATCH * 3;
    const int*   __restrict__ nb_b  = neighbors + (size_t)b * PER_BATCH;
    const int*   __restrict__ mk_b  = mask      + (size_t)b * PER_BATCH;

    // ---- stage positions -> LDS [N][4], vectorized (4 rows per 3 x4-loads) ----
    #pragma unroll
    for (int g0 = 0; g0 < 2; ++g0) {
        const int g = g0 * THREADS + t;            // 0..2047 (4 rows each)
        const f32x4 v0 = *(const f32x4*)(pos_b + 12 * (size_t)g);
        const f32x4 v1 = *(const f32x4*)(pos_b + 12 * (size_t)g + 4);
        const f32x4 v2 = *(const f32x4*)(pos_b + 12 * (size_t)g + 8);
        f32x4 r0; r0.x = v0.x; r0.y = v0.y; r0.z = v0.z; r0.w = 0.0f;
        f32x4 r1; r1.x = v0.w; r1.y = v1.x; r1.z = v1.y; r1.w = 0.0f;
        f32x4 r2; r2.x = v1.z; r2.y = v1.w; r2.z = v2.x; r2.w = 0.0f;
        f32x4 r3; r3.x = v2.y; r3.y = v2.z; r3.z = v2.w; r3.w = 0.0f;
        spos[4 * g + 0] = r0;
        spos[4 * g + 1] = r1;
        spos[4 * g + 2] = r2;
        spos[4 * g + 3] = r3;
    }
    __syncthreads();

    const float* cb = cell + b * 9;
    const float c00 = cb[0], c01 = cb[1], c02 = cb[2];
    const float c10 = cb[3], c11 = cb[4], c12 = cb[5];
    const float c20 = cb[6], c21 = cb[7], c22 = cb[8];

    const int qbase = chunk * QUADS_PER_BLOCK;
    auto qat = [&](int k) { return qbase + k * THREADS + t; };

    struct Quad { i32x4 nb, mk; f32x4 oa, ob, oc; };
    auto loadq = [&](int q) {
        Quad Q;
        Q.nb = *(const i32x4*)(nb_b  + 4 * (size_t)q);
        Q.mk = *(const i32x4*)(mk_b  + 4 * (size_t)q);
        Q.oa = *(const f32x4*)(off_b + 12 * (size_t)q);
        Q.ob = *(const f32x4*)(off_b + 12 * (size_t)q + 4);
        Q.oc = *(const f32x4*)(off_b + 12 * (size_t)q + 8);
        return Q;
    };

    float acc = 0.0f;
    auto computeq = [&](const Quad& Q, int q) {
        const int n = q / 25;                 // 25 quads per row (K=100)
        const f32x4 pi = spos[n];
        auto elem = [&](int m, int j, float o0, float o1, float o2) {
            const f32x4 pj = spos[j];
            const float vx = pj.x + o0 * c00 + o1 * c10 + o2 * c20 - pi.x;
            const float vy = pj.y + o0 * c01 + o1 * c11 + o2 * c21 - pi.y;
            const float vz = pj.z + o0 * c02 + o1 * c12 + o2 * c22 - pi.z;
            const float sq = vx * vx + vy * vy + vz * vz;
            const bool keep = (m > 0) & (sq >= RMIN2) & (sq <= RMAX2);
            acc += keep ? (1.0f / sq) : 0.0f;
        };
        elem(Q.mk.x, Q.nb.x, Q.oa.x, Q.oa.y, Q.oa.z);
        elem(Q.mk.y, Q.nb.y, Q.oa.w, Q.ob.x, Q.ob.y);
        elem(Q.mk.z, Q.nb.z, Q.ob.z, Q.ob.w, Q.oc.x);
        elem(Q.mk.w, Q.nb.w, Q.oc.y, Q.oc.z, Q.oc.w);
    };

    // ---- software-pipelined main loop: load k+1 while computing k ----
    Quad cur = loadq(qat(0));
    #pragma unroll
    for (int k = 0; k < FULL_ITERS - 1; ++k) {
        Quad nxt = loadq(qat(k + 1));
        computeq(cur, qat(k));
        cur = nxt;
    }
    const bool hastail = t < TAIL;
    if (hastail) {
        Quad tq = loadq(qat(FULL_ITERS));
        computeq(cur, qat(FULL_ITERS - 1));
        computeq(tq, qat(FULL_ITERS));
    } else {
        computeq(cur, qat(FULL_ITERS - 1));
    }

    // ---- reduce ----
    #pragma unroll
    for (int off = 32; off > 0; off >>= 1)
        acc += __shfl_down(acc, off, 64);

    const int wave = t >> 6;
    const int lane = t & 63;
    if (lane == 0) wsum[wave] = acc;
    __syncthreads();
    if (t == 0) {
        float s = 0.0f;
        #pragma unroll
        for (int w = 0; w < THREADS / 64; ++w) s += wsum[w];
        atomicAdd(&out[b], 0.5f * s);
    }
}

extern "C" void kernel_launch(void* const* d_in, const int* in_sizes, int n_in,
                              void* d_out, int out_size, void* d_ws, size_t ws_size,
                              hipStream_t stream) {
    const float* positions = (const float*)d_in[0];
    const float* cell      = (const float*)d_in[1];
    const float* offsets   = (const float*)d_in[2];
    const int*   neighbors = (const int*)d_in[3];
    const int*   mask      = (const int*)d_in[4];
    float* out = (float*)d_out;

    (void)hipMemsetAsync(out, 0, out_size * sizeof(float), stream);

    repulsive_prior_kernel<<<GRID, THREADS, 0, stream>>>(
        positions, cell, offsets, neighbors, mask, out);
}

// Round 9
// 32.343 us; speedup vs baseline: 1.0208x; 1.0208x over previous
//
#include <hip/hip_runtime.h>

typedef int   __attribute__((ext_vector_type(4))) i32x4;
typedef float __attribute__((ext_vector_type(4))) f32x4;

constexpr int B_ = 8;
constexpr int N_ = 8192;
constexpr int K_ = 100;
constexpr int PER_BATCH = N_ * K_;                 // 819200 elements
constexpr int QUADS_PER_BATCH = PER_BATCH / 4;     // 204800 quads
constexpr int THREADS = 1024;                      // 16 waves
constexpr int BLOCKS_PER_BATCH = 32;
constexpr int GRID = B_ * BLOCKS_PER_BATCH;        // 256 blocks -> 1/CU (128KB LDS)
constexpr int QUADS_PER_BLOCK = QUADS_PER_BATCH / BLOCKS_PER_BATCH; // 6400
constexpr int FULL_ITERS = QUADS_PER_BLOCK / THREADS;               // 6
constexpr int TAIL = QUADS_PER_BLOCK - FULL_ITERS * THREADS;        // 256

constexpr float RMIN2 = 0.01f;   // 0.1^2
constexpr float RMAX2 = 4.0f;    // 2.0^2

__global__ __launch_bounds__(THREADS, 1)
void repulsive_prior_kernel(const float* __restrict__ positions,  // [B,N,3]
                            const float* __restrict__ cell,       // [B,3,3]
                            const float* __restrict__ offsets,    // [B,N,K,3]
                            const int*   __restrict__ neighbors,  // [B,N,K]
                            const int*   __restrict__ mask,       // [B,N,K]
                            float* __restrict__ out)              // [B]
{
    __shared__ f32x4 spos[N_];            // 128 KB: xyz + pad -> 1 ds_read_b128/gather
    __shared__ float wsum[THREADS / 64];

    const int bid   = blockIdx.x;
    const int b     = bid >> 5;            // 32 blocks per batch
    const int chunk = bid & 31;
    const int t     = (int)threadIdx.x;

    const float* __restrict__ pos_b = positions + (size_t)b * N_ * 3;
    const float* __restrict__ off_b = offsets   + (size_t)b * PER_BATCH * 3;
    const int*   __restrict__ nb_b  = neighbors + (size_t)b * PER_BATCH;
    const int*   __restrict__ mk_b  = mask      + (size_t)b * PER_BATCH;

    const int qbase = chunk * QUADS_PER_BLOCK;
    auto qat = [&](int k) { return qbase + k * THREADS + t; };

    struct Quad { i32x4 nb, mk; f32x4 oa, ob, oc; };
    auto loadq = [&](int q) {
        Quad Q;
        Q.nb = *(const i32x4*)(nb_b  + 4 * (size_t)q);
        Q.mk = *(const i32x4*)(mk_b  + 4 * (size_t)q);
        Q.oa = *(const f32x4*)(off_b + 12 * (size_t)q);
        Q.ob = *(const f32x4*)(off_b + 12 * (size_t)q + 4);
        Q.oc = *(const f32x4*)(off_b + 12 * (size_t)q + 8);
        return Q;
    };

    // ---- issue first 3 iterations' stream loads BEFORE staging: they overlap
    //      the LDS fill + barrier ----
    Quad Q0 = loadq(qat(0));
    Quad Q1 = loadq(qat(1));
    Quad Q2 = loadq(qat(2));

    // ---- stage positions -> LDS [N][4], vectorized (4 rows per 3 x4-loads) ----
    #pragma unroll
    for (int g0 = 0; g0 < 2; ++g0) {
        const int g = g0 * THREADS + t;            // 0..2047 (4 rows each)
        const f32x4 v0 = *(const f32x4*)(pos_b + 12 * (size_t)g);
        const f32x4 v1 = *(const f32x4*)(pos_b + 12 * (size_t)g + 4);
        const f32x4 v2 = *(const f32x4*)(pos_b + 12 * (size_t)g + 8);
        f32x4 r0; r0.x = v0.x; r0.y = v0.y; r0.z = v0.z; r0.w = 0.0f;
        f32x4 r1; r1.x = v0.w; r1.y = v1.x; r1.z = v1.y; r1.w = 0.0f;
        f32x4 r2; r2.x = v1.z; r2.y = v1.w; r2.z = v2.x; r2.w = 0.0f;
        f32x4 r3; r3.x = v2.y; r3.y = v2.z; r3.z = v2.w; r3.w = 0.0f;
        spos[4 * g + 0] = r0;
        spos[4 * g + 1] = r1;
        spos[4 * g + 2] = r2;
        spos[4 * g + 3] = r3;
    }
    __syncthreads();

    const float* cb = cell + b * 9;
    const float c00 = cb[0], c01 = cb[1], c02 = cb[2];
    const float c10 = cb[3], c11 = cb[4], c12 = cb[5];
    const float c20 = cb[6], c21 = cb[7], c22 = cb[8];

    float acc = 0.0f;
    auto computeq = [&](const Quad& Q, int q) {
        const int n = q / 25;                 // 25 quads per row (K=100)
        const f32x4 pi = spos[n];
        auto elem = [&](int m, int j, float o0, float o1, float o2) {
            const f32x4 pj = spos[j];
            const float vx = pj.x + o0 * c00 + o1 * c10 + o2 * c20 - pi.x;
            const float vy = pj.y + o0 * c01 + o1 * c11 + o2 * c21 - pi.y;
            const float vz = pj.z + o0 * c02 + o1 * c12 + o2 * c22 - pi.z;
            const float sq = vx * vx + vy * vy + vz * vz;
            const bool keep = (m > 0) & (sq >= RMIN2) & (sq <= RMAX2);
            acc += keep ? (1.0f / sq) : 0.0f;
        };
        elem(Q.mk.x, Q.nb.x, Q.oa.x, Q.oa.y, Q.oa.z);
        elem(Q.mk.y, Q.nb.y, Q.oa.w, Q.ob.x, Q.ob.y);
        elem(Q.mk.z, Q.nb.z, Q.ob.z, Q.ob.w, Q.oc.x);
        elem(Q.mk.w, Q.nb.w, Q.oc.y, Q.oc.z, Q.oc.w);
    };

    // ---- depth-3 software pipeline, fully unrolled, static rotation ----
    // FULL_ITERS = 6: compute k while k+1, k+2 are in flight; load k+3.
    Q0 = Q0; // (named rotation below keeps all indices compile-time)
    {
        Quad Q3 = loadq(qat(3));
        computeq(Q0, qat(0));
        Quad Q4 = loadq(qat(4));
        computeq(Q1, qat(1));
        Quad Q5 = loadq(qat(5));
        computeq(Q2, qat(2));
        // tail-overlapped drain
        const bool hastail = t < TAIL;
        if (hastail) {
            Quad Q6 = loadq(qat(6));
            computeq(Q3, qat(3));
            computeq(Q4, qat(4));
            computeq(Q5, qat(5));
            computeq(Q6, qat(6));
        } else {
            computeq(Q3, qat(3));
            computeq(Q4, qat(4));
            computeq(Q5, qat(5));
        }
    }

    // ---- reduce ----
    #pragma unroll
    for (int off = 32; off > 0; off >>= 1)
        acc += __shfl_down(acc, off, 64);

    const int wave = t >> 6;
    const int lane = t & 63;
    if (lane == 0) wsum[wave] = acc;
    __syncthreads();
    if (t == 0) {
        float s = 0.0f;
        #pragma unroll
        for (int w = 0; w < THREADS / 64; ++w) s += wsum[w];
        atomicAdd(&out[b], 0.5f * s);
    }
}

extern "C" void kernel_launch(void* const* d_in, const int* in_sizes, int n_in,
                              void* d_out, int out_size, void* d_ws, size_t ws_size,
                              hipStream_t stream) {
    const float* positions = (const float*)d_in[0];
    const float* cell      = (const float*)d_in[1];
    const float* offsets   = (const float*)d_in[2];
    const int*   neighbors = (const int*)d_in[3];
    const int*   mask      = (const int*)d_in[4];
    float* out = (float*)d_out;

    (void)hipMemsetAsync(out, 0, out_size * sizeof(float), stream);

    repulsive_prior_kernel<<<GRID, THREADS, 0, stream>>>(
        positions, cell, offsets, neighbors, mask, out);
}

// Round 10
// 31.490 us; speedup vs baseline: 1.0485x; 1.0271x over previous
//
#include <hip/hip_runtime.h>
#include <hip/hip_fp16.h>

typedef int            __attribute__((ext_vector_type(4))) i32x4;
typedef float          __attribute__((ext_vector_type(4))) f32x4;
typedef unsigned int   __attribute__((ext_vector_type(2))) u32x2;

constexpr int B_ = 8;
constexpr int N_ = 8192;
constexpr int K_ = 100;
constexpr int PER_BATCH = N_ * K_;                 // 819200 elements
constexpr int QUADS_PER_BATCH = PER_BATCH / 4;     // 204800 quads
constexpr int THREADS = 1024;                      // 16 waves
constexpr int BLOCKS_PER_BATCH = 64;
constexpr int GRID = B_ * BLOCKS_PER_BATCH;        // 512 blocks -> 2/CU (64KB LDS each)
constexpr int QUADS_PER_BLOCK = QUADS_PER_BATCH / BLOCKS_PER_BATCH; // 3200
constexpr int FULL_ITERS = QUADS_PER_BLOCK / THREADS;               // 3
constexpr int TAIL = QUADS_PER_BLOCK - FULL_ITERS * THREADS;        // 128

constexpr float RMIN2 = 0.01f;   // 0.1^2
constexpr float RMAX2 = 4.0f;    // 2.0^2

__device__ __forceinline__ u32x2 pack_pos(float x, float y, float z) {
    const unsigned hx = __half_as_ushort(__float2half_rn(x));
    const unsigned hy = __half_as_ushort(__float2half_rn(y));
    const unsigned hz = __half_as_ushort(__float2half_rn(z));
    u32x2 r; r.x = hx | (hy << 16); r.y = hz;
    return r;
}

__global__ __launch_bounds__(THREADS, 2)
void repulsive_prior_kernel(const float* __restrict__ positions,  // [B,N,3]
                            const float* __restrict__ cell,       // [B,3,3]
                            const float* __restrict__ offsets,    // [B,N,K,3]
                            const int*   __restrict__ neighbors,  // [B,N,K]
                            const int*   __restrict__ mask,       // [B,N,K]
                            float* __restrict__ out)              // [B]
{
    __shared__ u32x2 spos[N_];            // 64 KB: xyz as f16 -> 1 ds_read_b64/gather
    __shared__ float wsum[THREADS / 64];

    const int bid   = blockIdx.x;
    const int b     = bid & 7;             // XCD-affine batch mapping
    const int chunk = bid >> 3;            // 0..63
    const int t     = (int)threadIdx.x;

    const float* __restrict__ pos_b = positions + (size_t)b * N_ * 3;
    const float* __restrict__ off_b = offsets   + (size_t)b * PER_BATCH * 3;
    const int*   __restrict__ nb_b  = neighbors + (size_t)b * PER_BATCH;
    const int*   __restrict__ mk_b  = mask      + (size_t)b * PER_BATCH;

    const int qbase = chunk * QUADS_PER_BLOCK;
    auto qat = [&](int k) { return qbase + k * THREADS + t; };

    struct Quad { i32x4 nb, mk; f32x4 oa, ob, oc; };
    auto loadq = [&](int q) {
        Quad Q;
        Q.nb = *(const i32x4*)(nb_b  + 4 * (size_t)q);
        Q.mk = *(const i32x4*)(mk_b  + 4 * (size_t)q);
        Q.oa = *(const f32x4*)(off_b + 12 * (size_t)q);
        Q.ob = *(const f32x4*)(off_b + 12 * (size_t)q + 4);
        Q.oc = *(const f32x4*)(off_b + 12 * (size_t)q + 8);
        return Q;
    };

    // pre-issue iteration 0's stream loads; they overlap the staging + barrier
    Quad Q0 = loadq(qat(0));

    // ---- stage positions -> LDS as packed f16 (4 rows per 3 x4-loads) ----
    #pragma unroll
    for (int g0 = 0; g0 < 2; ++g0) {
        const int g = g0 * THREADS + t;            // 0..2047 (4 rows each)
        const f32x4 v0 = *(const f32x4*)(pos_b + 12 * (size_t)g);
        const f32x4 v1 = *(const f32x4*)(pos_b + 12 * (size_t)g + 4);
        const f32x4 v2 = *(const f32x4*)(pos_b + 12 * (size_t)g + 8);
        spos[4 * g + 0] = pack_pos(v0.x, v0.y, v0.z);
        spos[4 * g + 1] = pack_pos(v0.w, v1.x, v1.y);
        spos[4 * g + 2] = pack_pos(v1.z, v1.w, v2.x);
        spos[4 * g + 3] = pack_pos(v2.y, v2.z, v2.w);
    }
    __syncthreads();

    const float* cb = cell + b * 9;
    const float c00 = cb[0], c01 = cb[1], c02 = cb[2];
    const float c10 = cb[3], c11 = cb[4], c12 = cb[5];
    const float c20 = cb[6], c21 = cb[7], c22 = cb[8];

    auto ldpos = [&](int row, float& x, float& y, float& z) {
        const u32x2 v = spos[row];
        x = __half2float(__ushort_as_half((unsigned short)(v.x & 0xffffu)));
        y = __half2float(__ushort_as_half((unsigned short)(v.x >> 16)));
        z = __half2float(__ushort_as_half((unsigned short)(v.y & 0xffffu)));
    };

    float acc = 0.0f;
    auto computeq = [&](const Quad& Q, int q) {
        const int n = q / 25;                 // 25 quads per row (K=100)
        float pix, piy, piz;
        ldpos(n, pix, piy, piz);
        auto elem = [&](int m, int j, float o0, float o1, float o2) {
            float pjx, pjy, pjz;
            ldpos(j, pjx, pjy, pjz);
            const float vx = pjx + o0 * c00 + o1 * c10 + o2 * c20 - pix;
            const float vy = pjy + o0 * c01 + o1 * c11 + o2 * c21 - piy;
            const float vz = pjz + o0 * c02 + o1 * c12 + o2 * c22 - piz;
            const float sq = vx * vx + vy * vy + vz * vz;
            const bool keep = (m > 0) & (sq >= RMIN2) & (sq <= RMAX2);
            acc += keep ? (1.0f / sq) : 0.0f;
        };
        elem(Q.mk.x, Q.nb.x, Q.oa.x, Q.oa.y, Q.oa.z);
        elem(Q.mk.y, Q.nb.y, Q.oa.w, Q.ob.x, Q.ob.y);
        elem(Q.mk.z, Q.nb.z, Q.ob.z, Q.ob.w, Q.oc.x);
        elem(Q.mk.w, Q.nb.w, Q.oc.y, Q.oc.z, Q.oc.w);
    };

    // ---- depth-2 pipeline over 3 full iters + tail ----
    Quad Q1 = loadq(qat(1));
    computeq(Q0, qat(0));
    Quad Q2 = loadq(qat(2));
    computeq(Q1, qat(1));
    if (t < TAIL) {
        Quad QT = loadq(qat(3));
        computeq(Q2, qat(2));
        computeq(QT, qat(3));
    } else {
        computeq(Q2, qat(2));
    }

    // ---- reduce ----
    #pragma unroll
    for (int off = 32; off > 0; off >>= 1)
        acc += __shfl_down(acc, off, 64);

    const int wave = t >> 6;
    const int lane = t & 63;
    if (lane == 0) wsum[wave] = acc;
    __syncthreads();
    if (t == 0) {
        float s = 0.0f;
        #pragma unroll
        for (int w = 0; w < THREADS / 64; ++w) s += wsum[w];
        atomicAdd(&out[b], 0.5f * s);
    }
}

extern "C" void kernel_launch(void* const* d_in, const int* in_sizes, int n_in,
                              void* d_out, int out_size, void* d_ws, size_t ws_size,
                              hipStream_t stream) {
    const float* positions = (const float*)d_in[0];
    const float* cell      = (const float*)d_in[1];
    const float* offsets   = (const float*)d_in[2];
    const int*   neighbors = (const int*)d_in[3];
    const int*   mask      = (const int*)d_in[4];
    float* out = (float*)d_out;

    (void)hipMemsetAsync(out, 0, out_size * sizeof(float), stream);

    repulsive_prior_kernel<<<GRID, THREADS, 0, stream>>>(
        positions, cell, offsets, neighbors, mask, out);
}